// Round 1
// baseline (236.493 us; speedup 1.0000x reference)
//
#include <hip/hip_runtime.h>
#include <stdint.h>

typedef unsigned short u16;
typedef __attribute__((ext_vector_type(4))) float floatx4;
typedef __attribute__((ext_vector_type(8))) short bf16x8;

#define MTOK   32768   // 512 windows * 64 tokens
#define KDIM   512
#define NQKV   1536
#define NWIN   512
#define N_HEAD 16
#define SECSZ  (512 * 16 * 2048)   // u16 elems per Q/K/V section (32 MB)
#define QK_SCALE 0.17677669529663687f  // 32^-0.5

__device__ __forceinline__ u16 f2bf(float f) {
  union { float f; unsigned u; } v; v.f = f;
  unsigned r = v.u + 0x7fffu + ((v.u >> 16) & 1u);
  return (u16)(r >> 16);
}

__device__ __forceinline__ void load_lds16(const void* g, void* l) {
  __builtin_amdgcn_global_load_lds((const __attribute__((address_space(1))) void*)g,
                                   (__attribute__((address_space(3))) void*)l,
                                   16, 0, 0);
}

// ---------------- kernel 1: fused converts (unchanged)
__global__ __launch_bounds__(256) void convert_xw(const float* __restrict__ x,
                                                  const float* __restrict__ wsrc,
                                                  u16* __restrict__ A,
                                                  u16* __restrict__ Wb) {
  int b = blockIdx.x;
  if (b < 768) {
    int e = (b * 256 + threadIdx.x) * 4;
    const float4 v = *(const float4*)(wsrc + e);
    ushort4 o;
    o.x = f2bf(v.x); o.y = f2bf(v.y); o.z = f2bf(v.z); o.w = f2bf(v.w);
    *(ushort4*)(Wb + e) = o;
  } else {
    int idx = (b - 768) * 256 + threadIdx.x;
    int e = idx * 4;
    int c = e & 511;
    int tg = e >> 9;
    int w = tg >> 6, t = tg & 63;
    int img = w >> 6, wy = (w >> 3) & 7, wx = w & 7;
    int ty = t >> 3, tx = t & 7;
    int y = wy * 8 + ty, xp = wx * 8 + tx;
    const float4 v = *(const float4*)(x + (((img * 64 + y) * 64 + xp) * 512 + c));
    ushort4 o;
    o.x = f2bf(v.x); o.y = f2bf(v.y); o.z = f2bf(v.z); o.w = f2bf(v.w);
    *(ushort4*)(A + e) = o;
  }
}

// ---------------- kernel 2: QKV GEMM — 256x256 tile, BK=64, 8-phase counted-vmcnt
// schedule (T3+T4), st-swizzled LDS (T2, both-sides involution), setprio (T5).
// 8 waves (2M x 4N), per-wave 128x64 output. LDS: 2 K-tile slots x (A 32KB + B 32KB).
// Staging: global_load_lds w=16, source pre-swizzled chunk^=(row&7); ds_read applies
// the same XOR -> conflict-free b128 reads. vmcnt(4) at tile starts (never 0 until tail).
// Epilogue = prior kernel's verified via-LDS transpose, scaled to 256^2 (bit-identical FP).
__global__ __launch_bounds__(512, 2) void gemm_qkv(const u16* __restrict__ A,
                                                   const u16* __restrict__ Wb,
                                                   const float* __restrict__ bias,
                                                   u16* __restrict__ QKV) {
  __shared__ __attribute__((aligned(16))) char smem[131072];

  int b = blockIdx.x;
  int lin = (b & 7) * 96 + (b >> 3);   // bijective XCD swizzle (768 % 8 == 0)
  int mtile = lin / 6;                 // [0,128)
  int ntile = lin % 6;                 // [0,6)

  const int tid = threadIdx.x;
  const int wv = tid >> 6, lane = tid & 63;
  const int il = lane & 15, ch = lane >> 4;
  const int wm = wv >> 2, wn = wv & 3;

  // staging: thread covers LDS (row = c*64 + tid>>3, chunk = tid&7); source chunk
  // pre-swizzled so LDS[row][chunk] = G[row][chunk ^ (row&7)]
  const int srow = tid >> 3;
  const int csw  = (tid & 7) ^ (srow & 7);
  const u16* gA = A  + (size_t)(mtile * 256 + srow) * KDIM + csw * 8;
  const u16* gB = Wb + (size_t)(ntile * 256 + srow) * KDIM + csw * 8;

#define STG_A(t_, c_) load_lds16(gA + (t_) * 64 + (c_) * 32768, smem + (((t_) & 1) * 65536) + (c_) * 8192 + wv * 1024)
#define STG_B(t_, c_) load_lds16(gB + (t_) * 64 + (c_) * 32768, smem + (((t_) & 1) * 65536) + 32768 + (c_) * 8192 + wv * 1024)

  // fragment read addressing (byte offsets); XOR swizzle matches staging involution
  const int abrow = (wm * 128 + il) * 128;
  const int bbrow = 32768 + (wn * 64 + il) * 128;
  const int sw0 = ((0 + ch) ^ (il & 7)) << 4;   // kk=0: chunk = ch
  const int sw1 = ((4 + ch) ^ (il & 7)) << 4;   // kk=1: chunk = 4+ch

  floatx4 acc[8][4];
  floatx4 zacc = {0.f, 0.f, 0.f, 0.f};
#pragma unroll
  for (int m = 0; m < 8; ++m)
#pragma unroll
    for (int n = 0; n < 4; ++n) acc[m][n] = zacc;

  // prologue: A(0), B(0), B(1) -> 12 loads in flight
  STG_A(0, 0); STG_A(0, 1); STG_A(0, 2); STG_A(0, 3);
  STG_B(0, 0); STG_B(0, 1); STG_B(0, 2); STG_B(0, 3);
  STG_B(1, 0); STG_B(1, 1); STG_B(1, 2); STG_B(1, 3);

#pragma unroll
  for (int t = 0; t < 8; ++t) {
    const int sb = (t & 1) * 65536;
    // tile t needs A(t),B(t) landed; newest 4 loads (B(t+1)) may stay in flight
    if (t == 7) asm volatile("s_waitcnt vmcnt(0)" ::: "memory");
    else        asm volatile("s_waitcnt vmcnt(4)" ::: "memory");
    __builtin_amdgcn_s_barrier();

    bf16x8 bf[4][2];
#pragma unroll
    for (int nt = 0; nt < 4; ++nt) {
      bf[nt][0] = *(const bf16x8*)(smem + sb + bbrow + nt * 2048 + sw0);
      bf[nt][1] = *(const bf16x8*)(smem + sb + bbrow + nt * 2048 + sw1);
    }

#pragma unroll
    for (int p = 0; p < 4; ++p) {
      const char* ab = smem + sb + abrow + p * 4096;
      bf16x8 a00 = *(const bf16x8*)(ab + sw0);
      bf16x8 a01 = *(const bf16x8*)(ab + sw1);
      bf16x8 a10 = *(const bf16x8*)(ab + 2048 + sw0);
      bf16x8 a11 = *(const bf16x8*)(ab + 2048 + sw1);

      // prefetch: A(t+1) in p0-p1 (its slot's last reader = tile t-1, done);
      // B(t+2) in p2-p3 (this slot's B readers finished in p0)
      if (p < 2) {
        if (t < 7) { STG_A(t + 1, p * 2); STG_A(t + 1, p * 2 + 1); }
      } else {
        if (t < 6) { STG_B(t + 2, p * 2 - 4); STG_B(t + 2, p * 2 - 3); }
      }

      __builtin_amdgcn_s_barrier();
      asm volatile("s_waitcnt lgkmcnt(0)" ::: "memory");
      __builtin_amdgcn_s_setprio(1);
#pragma unroll
      for (int nt = 0; nt < 4; ++nt) {
        acc[2 * p][nt]     = __builtin_amdgcn_mfma_f32_16x16x32_bf16(a00, bf[nt][0], acc[2 * p][nt], 0, 0, 0);
        acc[2 * p][nt]     = __builtin_amdgcn_mfma_f32_16x16x32_bf16(a01, bf[nt][1], acc[2 * p][nt], 0, 0, 0);
        acc[2 * p + 1][nt] = __builtin_amdgcn_mfma_f32_16x16x32_bf16(a10, bf[nt][0], acc[2 * p + 1][nt], 0, 0, 0);
        acc[2 * p + 1][nt] = __builtin_amdgcn_mfma_f32_16x16x32_bf16(a11, bf[nt][1], acc[2 * p + 1][nt], 0, 0, 0);
      }
      __builtin_amdgcn_s_setprio(0);
      __builtin_amdgcn_s_barrier();
    }
  }
#undef STG_A
#undef STG_B

  // ---- epilogue: rows R = wm*128 + mt*16 + ch*4 + r, cols C = wn*64 + nt*16 + il
  const int sec = ntile >> 1;           // 0=Q 1=K 2=V
  const int h0v = (ntile & 1) * 8;      // 8 heads per block
  const int gw0 = mtile * 4;            // 4 windows per block
  u16* dst = QKV + (size_t)sec * SECSZ;
  const float sc = (sec == 0) ? QK_SCALE : 1.0f;

  float bv[4];
#pragma unroll
  for (int nt = 0; nt < 4; ++nt) bv[nt] = bias[ntile * 256 + wn * 64 + nt * 16 + il];

  u16* Lt = (u16*)smem;

  for (int p = 0; p < 2; ++p) {         // pass p handles rows 128p..128p+127 (waves wm==p)
    if (wm == p) {
      if (sec < 2) {
        // Lt[t_local=128][c=256], row stride 264 u16 (528B = 33*16, aligned reads)
#pragma unroll
        for (int mt = 0; mt < 8; ++mt) {
          int tl = mt * 16 + ch * 4;
#pragma unroll
          for (int nt = 0; nt < 4; ++nt) {
            int cc = wn * 64 + nt * 16 + il;
#pragma unroll
            for (int r = 0; r < 4; ++r)
              Lt[(tl + r) * 264 + cc] = f2bf((acc[mt][nt][r] + bv[nt]) * sc);
          }
        }
      } else {
        // V transposed: Lt[c=256][t_local=128], row stride 136 u16 (272B = 17*16)
#pragma unroll
        for (int mt = 0; mt < 8; ++mt) {
          int tl = mt * 16 + ch * 4;
#pragma unroll
          for (int nt = 0; nt < 4; ++nt) {
            int cc = wn * 64 + nt * 16 + il;
            ushort4 pk;
            pk.x = f2bf(acc[mt][nt][0] + bv[nt]);
            pk.y = f2bf(acc[mt][nt][1] + bv[nt]);
            pk.z = f2bf(acc[mt][nt][2] + bv[nt]);
            pk.w = f2bf(acc[mt][nt][3] + bv[nt]);
            *(ushort4*)(Lt + cc * 136 + tl) = pk;
          }
        }
      }
    }
    asm volatile("s_waitcnt lgkmcnt(0)" ::: "memory");
    __builtin_amdgcn_s_barrier();

    if (sec < 2) {
      // 1024 (t,h) tasks, 2 per thread; 64B contiguous stores
#pragma unroll
      for (int i = 0; i < 2; ++i) {
        int task = tid + i * 512;
        int tl = task >> 3, hh = task & 7;
        const uint4* srcp = (const uint4*)(Lt + tl * 264 + hh * 32);
        uint4 v0 = srcp[0], v1 = srcp[1], v2 = srcp[2], v3 = srcp[3];
        int w = gw0 + 2 * p + (tl >> 6);
        uint4* o = (uint4*)(dst + (size_t)(w * 16 + h0v + hh) * 2048 + (tl & 63) * 32);
        o[0] = v0; o[1] = v1; o[2] = v2; o[3] = v3;
      }
    } else {
      // 512 (c,w) tasks, 1 per thread; 128B contiguous stores
      int c = tid >> 1, wl = tid & 1;
      const uint4* srcp = (const uint4*)(Lt + c * 136 + wl * 64);
      int w = gw0 + 2 * p + wl;
      uint4* o = (uint4*)(dst + (size_t)(w * 16 + h0v + (c >> 5)) * 2048 + (c & 31) * 64);
#pragma unroll
      for (int i = 0; i < 8; ++i) o[i] = srcp[i];
    }
    asm volatile("s_waitcnt lgkmcnt(0)" ::: "memory");
    __builtin_amdgcn_s_barrier();   // buffer free for next pass's writers
  }
}

// ---------------- kernel 3: attention, one block = (window, head) (unchanged)
__global__ __launch_bounds__(256) void attn(const u16* __restrict__ QKV,
                                            const float* __restrict__ btab,
                                            float* __restrict__ out) {
  __shared__ __attribute__((aligned(16))) u16 Pl[64 * 88];
  __shared__ float sbias[225];

  int bid = blockIdx.x;
  int w = bid >> 4, h = bid & 15;
  int tid = threadIdx.x;
  if (tid < 225) sbias[tid] = btab[tid * 16 + h];

  int lane = tid & 63, wv = tid >> 6;
  int il = lane & 15, ch = lane >> 4;
  const u16* Qb = QKV + (w * 16 + h) * 2048;
  const u16* Kb = Qb + SECSZ;
  const u16* Vt = Qb + 2 * (size_t)SECSZ;

  bf16x8 aq = *(const bf16x8*)(Qb + (wv * 16 + il) * 32 + ch * 8);
  floatx4 zacc = {0.f, 0.f, 0.f, 0.f};
  floatx4 s[4];
#pragma unroll
  for (int jt = 0; jt < 4; ++jt) {
    bf16x8 bk = *(const bf16x8*)(Kb + (jt * 16 + il) * 32 + ch * 8);
    s[jt] = __builtin_amdgcn_mfma_f32_16x16x32_bf16(aq, bk, zacc, 0, 0, 0);
  }

  __syncthreads();   // sbias visible

  int winidx = w & 63;
  int wy = winidx >> 3, wx = winidx & 7;
  float val[4][4];
#pragma unroll
  for (int r = 0; r < 4; ++r) {
    int i = wv * 16 + ch * 4 + r;
    int ty = i >> 3, tx = i & 7;
    int ry = (wy == 7) ? (ty < 4 ? 1 : 2) : 0;
    int rx = (wx == 7) ? (tx < 4 ? 1 : 2) : 0;
    int li = ry * 3 + rx;
#pragma unroll
    for (int jt = 0; jt < 4; ++jt) {
      int j = jt * 16 + il;
      int sy = j >> 3, sx = j & 7;
      int rjy = (wy == 7) ? (sy < 4 ? 1 : 2) : 0;
      int rjx = (wx == 7) ? (sx < 4 ? 1 : 2) : 0;
      float v = s[jt][r] + sbias[(ty - sy + 7) * 15 + (tx - sx + 7)];
      if (li != (rjy * 3 + rjx)) v -= 100.0f;
      val[r][jt] = v;
    }
  }

#pragma unroll
  for (int r = 0; r < 4; ++r) {
    float m = fmaxf(fmaxf(val[r][0], val[r][1]), fmaxf(val[r][2], val[r][3]));
    m = fmaxf(m, __shfl_xor(m, 1, 64));
    m = fmaxf(m, __shfl_xor(m, 2, 64));
    m = fmaxf(m, __shfl_xor(m, 4, 64));
    m = fmaxf(m, __shfl_xor(m, 8, 64));
    float sum = 0.f;
#pragma unroll
    for (int jt = 0; jt < 4; ++jt) { val[r][jt] = __expf(val[r][jt] - m); sum += val[r][jt]; }
    sum += __shfl_xor(sum, 1, 64);
    sum += __shfl_xor(sum, 2, 64);
    sum += __shfl_xor(sum, 4, 64);
    sum += __shfl_xor(sum, 8, 64);
    float inv = 1.0f / sum;
    int i = wv * 16 + ch * 4 + r;
#pragma unroll
    for (int jt = 0; jt < 4; ++jt)
      Pl[i * 88 + jt * 16 + il] = f2bf(val[r][jt] * inv);
  }

  __syncthreads();   // P visible

  floatx4 o0 = zacc, o1 = zacc;
#pragma unroll
  for (int kk = 0; kk < 2; ++kk) {
    bf16x8 ap  = *(const bf16x8*)((const u16*)Pl + (wv * 16 + il) * 88 + kk * 32 + ch * 8);
    bf16x8 bv0 = *(const bf16x8*)(Vt + il * 64 + kk * 32 + ch * 8);
    bf16x8 bv1 = *(const bf16x8*)(Vt + (16 + il) * 64 + kk * 32 + ch * 8);
    o0 = __builtin_amdgcn_mfma_f32_16x16x32_bf16(ap, bv0, o0, 0, 0, 0);
    o1 = __builtin_amdgcn_mfma_f32_16x16x32_bf16(ap, bv1, o1, 0, 0, 0);
  }

  int img = w >> 6;
#pragma unroll
  for (int r = 0; r < 4; ++r) {
    int i = wv * 16 + ch * 4 + r;
    int ty = i >> 3, tx = i & 7;
    int y = wy * 8 + ty, xp = wx * 8 + tx;
    float* op = out + ((img * 64 + y) * 64 + xp) * 512 + h * 32;
    op[il] = o0[r];
    op[16 + il] = o1[r];
  }
}

extern "C" void kernel_launch(void* const* d_in, const int* in_sizes, int n_in,
                              void* d_out, int out_size, void* d_ws, size_t ws_size,
                              hipStream_t stream) {
  const float* x      = (const float*)d_in[0];
  const float* qkv_w  = (const float*)d_in[1];
  const float* qkv_b  = (const float*)d_in[2];
  const float* btab   = (const float*)d_in[3];
  float* out = (float*)d_out;

  char* ws = (char*)d_ws;
  u16* A   = (u16*)ws;                                              // 32 MB
  u16* Wb  = (u16*)(ws + (size_t)MTOK * KDIM * 2);                  // 1.5 MB
  u16* QKV = (u16*)(ws + (size_t)MTOK * KDIM * 2 + (size_t)NQKV * KDIM * 2);  // 96 MB

  convert_xw<<<dim3(17152), dim3(256), 0, stream>>>(x, qkv_w, A, Wb);
  gemm_qkv<<<dim3(768), dim3(512), 0, stream>>>(A, Wb, qkv_b, QKV);
  attn<<<dim3(NWIN * N_HEAD), dim3(256), 0, stream>>>(QKV, btab, out);
}

// Round 2
// 226.898 us; speedup vs baseline: 1.0423x; 1.0423x over previous
//
#include <hip/hip_runtime.h>
#include <stdint.h>

typedef unsigned short u16;
typedef __attribute__((ext_vector_type(4))) float floatx4;
typedef __attribute__((ext_vector_type(8))) short bf16x8;

#define MTOK   32768   // 512 windows * 64 tokens
#define KDIM   512
#define NQKV   1536
#define NWIN   512
#define N_HEAD 16
#define SECSZ  (512 * 16 * 2048)   // u16 elems per Q/K/V section (32 MB)
#define QK_SCALE 0.17677669529663687f  // 32^-0.5

__device__ __forceinline__ u16 f2bf(float f) {
  union { float f; unsigned u; } v; v.f = f;
  unsigned r = v.u + 0x7fffu + ((v.u >> 16) & 1u);
  return (u16)(r >> 16);
}

__device__ __forceinline__ void load_lds16(const void* g, void* l) {
  __builtin_amdgcn_global_load_lds((const __attribute__((address_space(1))) void*)g,
                                   (__attribute__((address_space(3))) void*)l,
                                   16, 0, 0);
}

// ---------------- kernel 1: fused converts + bias/mask table gen
// blocks [0,768): qkv_w fp32->bf16; [768,17152): x -> window-ordered bf16 A;
// [17152,17216): per-(class,head) combined bias+mask table (4 cls x 16 h x 64 x 64 f32).
__global__ __launch_bounds__(256) void convert_xw(const float* __restrict__ x,
                                                  const float* __restrict__ wsrc,
                                                  const float* __restrict__ btab,
                                                  u16* __restrict__ A,
                                                  u16* __restrict__ Wb,
                                                  float* __restrict__ tbl) {
  int b = blockIdx.x;
  if (b < 768) {
    int e = (b * 256 + threadIdx.x) * 4;
    const float4 v = *(const float4*)(wsrc + e);
    ushort4 o;
    o.x = f2bf(v.x); o.y = f2bf(v.y); o.z = f2bf(v.z); o.w = f2bf(v.w);
    *(ushort4*)(Wb + e) = o;
  } else if (b < 17152) {
    int idx = (b - 768) * 256 + threadIdx.x;
    int e = idx * 4;
    int c = e & 511;
    int tg = e >> 9;
    int w = tg >> 6, t = tg & 63;
    int img = w >> 6, wy = (w >> 3) & 7, wx = w & 7;
    int ty = t >> 3, tx = t & 7;
    int y = wy * 8 + ty, xp = wx * 8 + tx;
    const float4 v = *(const float4*)(x + (((img * 64 + y) * 64 + xp) * 512 + c));
    ushort4 o;
    o.x = f2bf(v.x); o.y = f2bf(v.y); o.z = f2bf(v.z); o.w = f2bf(v.w);
    *(ushort4*)(A + e) = o;
  } else {
    int q = b - 17152;                 // [0,64): cls*16 + head
    int cls = q >> 4, hh = q & 15;
    int ey = cls >> 1, ex = cls & 1;   // edge flags: wy==7 / wx==7
    float* To = tbl + (q << 12);
#pragma unroll
    for (int e = 0; e < 16; ++e) {
      int idx = e * 256 + threadIdx.x;
      int i = idx >> 6, j = idx & 63;
      int ty = i >> 3, tx = i & 7, sy = j >> 3, sx = j & 7;
      int ry = ey ? (ty < 4 ? 1 : 2) : 0;
      int rx = ex ? (tx < 4 ? 1 : 2) : 0;
      int qy = ey ? (sy < 4 ? 1 : 2) : 0;
      int qx = ex ? (sx < 4 ? 1 : 2) : 0;
      float v = btab[((ty - sy + 7) * 15 + (tx - sx + 7)) * 16 + hh];
      if (ry * 3 + rx != qy * 3 + qx) v -= 100.0f;
      To[idx] = v;
    }
  }
}

// ---------------- kernel 2: QKV GEMM, bias fused, Q pre-scaled, V transposed
// 128x128 tile, BK=32, 4 blocks/CU (proven structure). This revision replaces the
// old 4-chunk staging XOR (4-way ds_read bank conflict, 7.2M cycles measured) with
// the 8-slot row-pair involution verified in R0: LDS dest linear, source chunk
// pre-permuted (R=row>>1 128B super-row, sub-slot c'=(row&1)*4+chunk, c'^=(R&7)),
// reads apply the same XOR -> 2-way (free).
__global__ __launch_bounds__(256, 4) void gemm_qkv(const u16* __restrict__ A,
                                                   const u16* __restrict__ Wb,
                                                   const float* __restrict__ bias,
                                                   u16* __restrict__ QKV) {
  __shared__ __attribute__((aligned(16))) char smem[18432];
  u16* Ct = (u16*)smem;

  int b = blockIdx.x;
  int xcd = b & 7, slot = b >> 3;
  int mtile = (slot / 12) * 8 + xcd;   // [0,256)
  int ntile = slot % 12;               // [0,12)

  int tid = threadIdx.x;
  int wv = tid >> 6, lane = tid & 63;
  int il = lane & 15, ch = lane >> 4;
  int wm = (wv & 1) * 64, wn = (wv >> 1) * 64;

  floatx4 acc[4][4];
  floatx4 zacc = {0.f, 0.f, 0.f, 0.f};
#pragma unroll
  for (int m = 0; m < 4; ++m)
#pragma unroll
    for (int n = 0; n < 4; ++n) acc[m][n] = zacc;

  // staging source swizzle (involution): thread tid fills LDS slot tid (16B),
  // content = G[row0, ch4] with s8 = (tid&7)^((tid>>3)&7)
  int s8   = (tid & 7) ^ ((tid >> 3) & 7);
  int row0 = ((tid >> 3) << 1) + (s8 >> 2);
  int ch4  = s8 & 3;
  const u16* Abase = A + (mtile * 128 + row0) * KDIM + ch4 * 8;
  const u16* Bbase = Wb + (ntile * 128 + row0) * KDIM + ch4 * 8;
  char* lAb = smem;
  char* lBb = smem + 8192;
  char* lA0 = lAb + wv * 1024;
  char* lA1 = lAb + 4096 + wv * 1024;
  char* lB0 = lBb + wv * 1024;
  char* lB1 = lBb + 4096 + wv * 1024;

  // read-side: slot is lane-constant; addr = (row>>1)*128 + slot*16
  int aslot = ((il & 1) * 4 + ch) ^ ((il >> 1) & 7);
  int fbase = (il >> 1) * 128 + aslot * 16;
  int awoff = (wv & 1) * 4096;   // (wm>>1)*128
  int bwoff = (wv >> 1) * 4096;  // (wn>>1)*128

  for (int kb = 0; kb < KDIM; kb += 32) {
    __syncthreads();
    load_lds16(Abase + kb, lA0);
    load_lds16(Abase + kb + 64 * KDIM, lA1);
    load_lds16(Bbase + kb, lB0);
    load_lds16(Bbase + kb + 64 * KDIM, lB1);
    __syncthreads();

    bf16x8 af[4], bfr[4];
#pragma unroll
    for (int mt = 0; mt < 4; ++mt)
      af[mt] = *(const bf16x8*)(lAb + awoff + fbase + mt * 1024);
#pragma unroll
    for (int nt = 0; nt < 4; ++nt)
      bfr[nt] = *(const bf16x8*)(lBb + bwoff + fbase + nt * 1024);
#pragma unroll
    for (int mt = 0; mt < 4; ++mt)
#pragma unroll
      for (int nt = 0; nt < 4; ++nt)
        acc[mt][nt] = __builtin_amdgcn_mfma_f32_16x16x32_bf16(af[mt], bfr[nt], acc[mt][nt], 0, 0, 0);
  }

  __syncthreads();   // K-loop LDS reads done before smem reuse

  // epilogue: C/D layout col=lane&15, row=(lane>>4)*4+reg
  int sec = ntile >> 2;              // 0=Q 1=K 2=V
  int h0 = (ntile & 3) * 4;          // 4 heads per block
  int gw0 = mtile * 2;               // 2 windows per block
  u16* dst = QKV + (size_t)sec * SECSZ;
  float sc = (sec == 0) ? QK_SCALE : 1.0f;

  for (int p = 0; p < 2; ++p) {      // pass p == window gw0+p (tokens p*64..p*64+63)
    if ((wv & 1) == p) {
      if (sec < 2) {
        // Ct[t_local=64][c=128], row stride 136 u16 (272B, 16*17 aligned)
#pragma unroll
        for (int nt = 0; nt < 4; ++nt) {
          float bv = bias[ntile * 128 + wn + nt * 16 + il];
          int cl = wn + nt * 16 + il;
#pragma unroll
          for (int mt = 0; mt < 4; ++mt) {
            int lr = mt * 16 + ch * 4;
#pragma unroll
            for (int r = 0; r < 4; ++r)
              Ct[(lr + r) * 136 + cl] = f2bf((acc[mt][nt][r] + bv) * sc);
          }
        }
      } else {
        // V transposed: Ct[c=128][t_local=64], row stride 72 u16 (144B, 16*9 aligned)
#pragma unroll
        for (int nt = 0; nt < 4; ++nt) {
          float bv = bias[ntile * 128 + wn + nt * 16 + il];
          int cl = wn + nt * 16 + il;
#pragma unroll
          for (int mt = 0; mt < 4; ++mt) {
            int lr = mt * 16 + ch * 4;
            ushort4 pk;
            pk.x = f2bf(acc[mt][nt][0] + bv);
            pk.y = f2bf(acc[mt][nt][1] + bv);
            pk.z = f2bf(acc[mt][nt][2] + bv);
            pk.w = f2bf(acc[mt][nt][3] + bv);
            *(ushort4*)(Ct + cl * 72 + lr) = pk;
          }
        }
      }
    }
    __syncthreads();

    if (sec < 2) {
      int tl = tid >> 2, dc = tid & 3;
#pragma unroll
      for (int hl = 0; hl < 4; ++hl) {
        uint4 v = *(const uint4*)(smem + tl * 272 + hl * 64 + dc * 16);
        *(uint4*)(dst + ((gw0 + p) * 16 + h0 + hl) * 2048 + tl * 32 + dc * 8) = v;
      }
    } else {
      int c0 = tid >> 3, tq = tid & 7;   // c0: d in [0,32), tq: t-chunk
#pragma unroll
      for (int hl = 0; hl < 4; ++hl) {
        uint4 v = *(const uint4*)(smem + (hl * 32 + c0) * 144 + tq * 16);
        *(uint4*)(dst + ((gw0 + p) * 16 + h0 + hl) * 2048 + c0 * 64 + tq * 8) = v;
      }
    }
    __syncthreads();   // buffer free for next pass's writers
  }
}

// ---------------- kernel 3: attention, one block = (window, head)
// bias+mask now a precomputed per-(class,head) table -> inner loop is one
// global load + add per element (was ~15 VALU); sbias LDS + its barrier deleted.
__global__ __launch_bounds__(256) void attn(const u16* __restrict__ QKV,
                                            const float* __restrict__ tbl,
                                            float* __restrict__ out) {
  __shared__ __attribute__((aligned(16))) u16 Pl[64 * 88];

  int bid = blockIdx.x;
  int w = bid >> 4, h = bid & 15;
  int tid = threadIdx.x;

  int lane = tid & 63, wv = tid >> 6;
  int il = lane & 15, ch = lane >> 4;
  const u16* Qb = QKV + (w * 16 + h) * 2048;
  const u16* Kb = Qb + SECSZ;
  const u16* Vt = Qb + 2 * (size_t)SECSZ;

  // S = Q K^T (Q already scaled); contiguous 16B frag loads
  bf16x8 aq = *(const bf16x8*)(Qb + (wv * 16 + il) * 32 + ch * 8);
  floatx4 zacc = {0.f, 0.f, 0.f, 0.f};
  floatx4 s[4];
#pragma unroll
  for (int jt = 0; jt < 4; ++jt) {
    bf16x8 bk = *(const bf16x8*)(Kb + (jt * 16 + il) * 32 + ch * 8);
    s[jt] = __builtin_amdgcn_mfma_f32_16x16x32_bf16(aq, bk, zacc, 0, 0, 0);
  }

  int winidx = w & 63;
  int wy = winidx >> 3, wx = winidx & 7;
  int cls = ((wy == 7) ? 2 : 0) | ((wx == 7) ? 1 : 0);
  const float* T = tbl + (((cls << 4) | h) << 12);

  float val[4][4];
#pragma unroll
  for (int r = 0; r < 4; ++r) {
    int i = wv * 16 + ch * 4 + r;
#pragma unroll
    for (int jt = 0; jt < 4; ++jt)
      val[r][jt] = s[jt][r] + T[i * 64 + jt * 16 + il];
  }

#pragma unroll
  for (int r = 0; r < 4; ++r) {
    float m = fmaxf(fmaxf(val[r][0], val[r][1]), fmaxf(val[r][2], val[r][3]));
    m = fmaxf(m, __shfl_xor(m, 1, 64));
    m = fmaxf(m, __shfl_xor(m, 2, 64));
    m = fmaxf(m, __shfl_xor(m, 4, 64));
    m = fmaxf(m, __shfl_xor(m, 8, 64));
    float sum = 0.f;
#pragma unroll
    for (int jt = 0; jt < 4; ++jt) { val[r][jt] = __expf(val[r][jt] - m); sum += val[r][jt]; }
    sum += __shfl_xor(sum, 1, 64);
    sum += __shfl_xor(sum, 2, 64);
    sum += __shfl_xor(sum, 4, 64);
    sum += __shfl_xor(sum, 8, 64);
    float inv = 1.0f / sum;
    int i = wv * 16 + ch * 4 + r;
#pragma unroll
    for (int jt = 0; jt < 4; ++jt)
      Pl[i * 88 + jt * 16 + il] = f2bf(val[r][jt] * inv);
  }

  __syncthreads();   // P visible

  // O = P V : V^T frags straight from global ([d][t] layout)
  floatx4 o0 = zacc, o1 = zacc;
#pragma unroll
  for (int kk = 0; kk < 2; ++kk) {
    bf16x8 ap  = *(const bf16x8*)((const u16*)Pl + (wv * 16 + il) * 88 + kk * 32 + ch * 8);
    bf16x8 bv0 = *(const bf16x8*)(Vt + il * 64 + kk * 32 + ch * 8);
    bf16x8 bv1 = *(const bf16x8*)(Vt + (16 + il) * 64 + kk * 32 + ch * 8);
    o0 = __builtin_amdgcn_mfma_f32_16x16x32_bf16(ap, bv0, o0, 0, 0, 0);
    o1 = __builtin_amdgcn_mfma_f32_16x16x32_bf16(ap, bv1, o1, 0, 0, 0);
  }

  int img = w >> 6;
#pragma unroll
  for (int r = 0; r < 4; ++r) {
    int i = wv * 16 + ch * 4 + r;
    int ty = i >> 3, tx = i & 7;
    int y = wy * 8 + ty, xp = wx * 8 + tx;
    float* op = out + ((img * 64 + y) * 64 + xp) * 512 + h * 32;
    op[il] = o0[r];
    op[16 + il] = o1[r];
  }
}

extern "C" void kernel_launch(void* const* d_in, const int* in_sizes, int n_in,
                              void* d_out, int out_size, void* d_ws, size_t ws_size,
                              hipStream_t stream) {
  const float* x      = (const float*)d_in[0];
  const float* qkv_w  = (const float*)d_in[1];
  const float* qkv_b  = (const float*)d_in[2];
  const float* btab   = (const float*)d_in[3];
  float* out = (float*)d_out;

  char* ws = (char*)d_ws;
  u16* A    = (u16*)ws;                                              // 32 MB
  u16* Wb   = (u16*)(ws + (size_t)MTOK * KDIM * 2);                  // 1.5 MB
  u16* QKV  = (u16*)(ws + (size_t)MTOK * KDIM * 2 + (size_t)NQKV * KDIM * 2);  // 96 MB
  float* tbl = (float*)(ws + (size_t)MTOK * KDIM * 2 + (size_t)NQKV * KDIM * 2
                           + 3 * (size_t)SECSZ * 2);                 // 1 MB

  convert_xw<<<dim3(17216), dim3(256), 0, stream>>>(x, qkv_w, btab, A, Wb, tbl);
  gemm_qkv<<<dim3(3072), dim3(256), 0, stream>>>(A, Wb, qkv_b, QKV);
  attn<<<dim3(NWIN * N_HEAD), dim3(256), 0, stream>>>(QKV, tbl, out);
}